// Round 15
// baseline (650.887 us; speedup 1.0000x reference)
//
#include <hip/hip_runtime.h>
#include <hip/hip_bf16.h>
#include <math.h>

#define H 1024
#define F 3584
#define F2 7168
#define NE 8
#define T 1024

typedef __attribute__((ext_vector_type(4))) float f32x4;
typedef __attribute__((ext_vector_type(8))) short bf16x8;
typedef __attribute__((ext_vector_type(4))) unsigned u32x4;

__device__ inline short f2bf(float f) {
  union { float f; unsigned u; } v; v.f = f;
  unsigned r = (v.u + 0x7FFFu + ((v.u >> 16) & 1u)) >> 16;
  return (short)r;
}

__device__ inline unsigned pkbf(float a, float b) {
  unsigned r;
  asm("v_cvt_pk_bf16_f32 %0, %1, %2" : "=v"(r) : "v"(a), "v"(b));
  return r;
}

#define MFMA16(af, bf, c) __builtin_amdgcn_mfma_f32_16x16x32_bf16((af), (bf), (c), 0, 0, 0)

// ---------------- x -> bf16 prepass ----------------
__global__ __launch_bounds__(256) void cvtx_k(
    const float* __restrict__ x, unsigned short* __restrict__ xb)
{
  int i = (blockIdx.x * 256 + threadIdx.x) * 8;
  f32x4 a = *(const f32x4*)(x + i);
  f32x4 b = *(const f32x4*)(x + i + 4);
  u32x4 o;
  o[0] = pkbf(a[0], a[1]); o[1] = pkbf(a[2], a[3]);
  o[2] = pkbf(b[0], b[1]); o[3] = pkbf(b[2], b[3]);
  *(u32x4*)(xb + i) = o;
}

// ---------------- router: fp64 logits, top-2 ----------------
__global__ __launch_bounds__(64) void router_k(
    const float* __restrict__ x, const float* __restrict__ gw,
    float* __restrict__ logits, int* __restrict__ cnt,
    int* __restrict__ tok_e, int* __restrict__ tok_r, float* __restrict__ tok_w)
{
  int t = blockIdx.x, l = threadIdx.x;
  const float* xr = x + (size_t)t * H;
  double acc[NE];
  #pragma unroll
  for (int e = 0; e < NE; ++e) acc[e] = 0.0;
  for (int j = 0; j < H / 64; ++j) {
    int h = j * 64 + l;
    float xv = xr[h];
    #pragma unroll
    for (int e = 0; e < NE; ++e) acc[e] += (double)xv * (double)gw[e * H + h];
  }
  #pragma unroll
  for (int off = 32; off >= 1; off >>= 1) {
    #pragma unroll
    for (int e = 0; e < NE; ++e) acc[e] += __shfl_down(acc[e], off, 64);
  }
  if (l == 0) {
    float lg[NE];
    #pragma unroll
    for (int e = 0; e < NE; ++e) { lg[e] = (float)acc[e]; logits[t * NE + e] = lg[e]; }
    int i0 = 0;
    for (int e = 1; e < NE; ++e) if (lg[e] > lg[i0]) i0 = e;
    int i1 = (i0 == 0) ? 1 : 0;
    for (int e = 0; e < NE; ++e) if (e != i0 && lg[e] > lg[i1]) i1 = e;
    float w0 = 1.f / (1.f + expf(lg[i1] - lg[i0]));
    float w1 = 1.f / (1.f + expf(lg[i0] - lg[i1]));
    int r0 = atomicAdd(&cnt[i0], 1);
    int r1 = atomicAdd(&cnt[i1], 1);
    tok_e[2 * t] = i0;     tok_r[2 * t] = r0;     tok_w[2 * t] = w0;
    tok_e[2 * t + 1] = i1; tok_r[2 * t + 1] = r1; tok_w[2 * t + 1] = w1;
  }
}

// ---------------- scan + gather list ----------------
__global__ __launch_bounds__(1024) void build_k(
    const int* __restrict__ cnt, int* __restrict__ base,
    const int* __restrict__ tok_e, const int* __restrict__ tok_r,
    const float* __restrict__ tok_w, int* __restrict__ gtok, float* __restrict__ gws)
{
  __shared__ int sb[NE];
  if (threadIdx.x == 0) {
    int s = 0;
    for (int e = 0; e < NE; ++e) { sb[e] = s; base[e] = s; s += cnt[e]; }
  }
  __syncthreads();
  int t = threadIdx.x;
  #pragma unroll
  for (int k = 0; k < 2; ++k) {
    int e = tok_e[2 * t + k];
    int slot = sb[e] + tok_r[2 * t + k];
    gtok[slot] = t;
    gws[slot] = tok_w[2 * t + k];
  }
}

// ---------------- ffn1: 1-wave blocks, M=128 x N=32 (16 gate + 16 up), BK=32 ----------------
// No LDS, no barriers. Per phase: 16 coalesced B dwords (cvt_pk in reg),
// 8 direct-global bf16 A frags, 16 MFMA. TLP (~14 waves/CU) hides latency.
__global__ __launch_bounds__(64, 3) void ffn1_k(
    const unsigned short* __restrict__ xb, const float* __restrict__ wgu,
    const int* __restrict__ cnt, const int* __restrict__ base,
    const int* __restrict__ gtok, unsigned short* __restrict__ act)
{
  // 7168 blocks = 8 XCD * 896 (e = xcd); per XCD: 224 p * 4 mB, mB fastest
  int e = blockIdx.x & 7;
  int idx = blockIdx.x >> 3;          // 0..895
  int mB = idx & 3;
  int p = idx >> 2;                   // 0..223
  int n = cnt[e];
  int m0 = mB * 128;
  if (m0 >= n) return;
  int sb = base[e];
  int lane = threadIdx.x;
  int lr = lane & 15, lg = lane >> 4;

  // B per-lane dword bases: gate col p*16+lr, up col F+p*16+lr, k = lg*8
  const float* Bg = wgu + (size_t)e * H * F2 + (size_t)(lg * 8) * F2 + p * 16 + lr;
  const float* Bu = Bg + F;

  // A per-lane row pointers (token gather, clamped)
  const unsigned short* ax[8];
  #pragma unroll
  for (int mf = 0; mf < 8; ++mf) {
    int sl = m0 + mf * 16 + lr; if (sl >= n) sl = n - 1;
    ax[mf] = xb + (size_t)gtok[sb + sl] * H + lg * 8;
  }

  f32x4 acc[8][2];
  #pragma unroll
  for (int mf = 0; mf < 8; ++mf) { acc[mf][0] = (f32x4)0.f; acc[mf][1] = (f32x4)0.f; }

  for (int s = 0; s < 32; ++s) {
    const float* bg = Bg + (size_t)s * 32 * F2;
    const float* bu = Bu + (size_t)s * 32 * F2;
    float g0 = bg[0],            g1 = bg[(size_t)1 * F2], g2 = bg[(size_t)2 * F2], g3 = bg[(size_t)3 * F2];
    float g4 = bg[(size_t)4 * F2], g5 = bg[(size_t)5 * F2], g6 = bg[(size_t)6 * F2], g7 = bg[(size_t)7 * F2];
    float u0 = bu[0],            u1 = bu[(size_t)1 * F2], u2 = bu[(size_t)2 * F2], u3 = bu[(size_t)3 * F2];
    float u4 = bu[(size_t)4 * F2], u5 = bu[(size_t)5 * F2], u6 = bu[(size_t)6 * F2], u7 = bu[(size_t)7 * F2];
    union { u32x4 u; bf16x8 h; } cg, cu;
    cg.u[0] = pkbf(g0, g1); cg.u[1] = pkbf(g2, g3);
    cg.u[2] = pkbf(g4, g5); cg.u[3] = pkbf(g6, g7);
    cu.u[0] = pkbf(u0, u1); cu.u[1] = pkbf(u2, u3);
    cu.u[2] = pkbf(u4, u5); cu.u[3] = pkbf(u6, u7);
    bf16x8 b0 = cg.h, b1 = cu.h;
    #pragma unroll
    for (int mf = 0; mf < 8; ++mf) {
      bf16x8 af = *(const bf16x8*)(ax[mf] + s * 32);
      acc[mf][0] = MFMA16(af, b0, acc[mf][0]);
      acc[mf][1] = MFMA16(af, b1, acc[mf][1]);
    }
  }

  // epilogue: silu(gate)*up
  int fcol = p * 16 + lr;
  #pragma unroll
  for (int mf = 0; mf < 8; ++mf) {
    #pragma unroll
    for (int r = 0; r < 4; ++r) {
      int sl = m0 + mf * 16 + lg * 4 + r;
      if (sl < n) {
        float gg = acc[mf][0][r], u = acc[mf][1][r];
        act[(size_t)(sb + sl) * F + fcol] = (unsigned short)f2bf(gg / (1.f + expf(-gg)) * u);
      }
    }
  }
}

// ---------------- ffn2: 1-wave blocks, M=128 x N=32, K-split x7 (512 each) ----------------
__global__ __launch_bounds__(64, 3) void ffn2_k(
    const unsigned short* __restrict__ act, const float* __restrict__ wd,
    const int* __restrict__ cnt, const int* __restrict__ base,
    const int* __restrict__ gtok, const float* __restrict__ gws,
    float* __restrict__ out)
{
  // 7168 blocks = 8 XCD * 896 (e = xcd); per XCD: 7 kh * 32 p * 4 mB, mB fastest
  int e = blockIdx.x & 7;
  int idx = blockIdx.x >> 3;          // 0..895
  int mB = idx & 3;
  int p = (idx >> 2) & 31;            // 0..31
  int kh = idx >> 7;                  // 0..6
  int n = cnt[e];
  int m0 = mB * 128;
  if (m0 >= n) return;
  int sb = base[e];
  int lane = threadIdx.x;
  int lr = lane & 15, lg = lane >> 4;
  const int kbase = kh * 512;

  // B per-lane dword bases: cols p*32+lr and p*32+16+lr
  const float* B0 = wd + (size_t)e * F * H + (size_t)(kbase + lg * 8) * H + p * 32 + lr;
  const float* B1 = B0 + 16;

  const unsigned short* ax[8];
  #pragma unroll
  for (int mf = 0; mf < 8; ++mf) {
    int sl = m0 + mf * 16 + lr; if (sl >= n) sl = n - 1;
    ax[mf] = act + (size_t)(sb + sl) * F + kbase + lg * 8;
  }

  f32x4 acc[8][2];
  #pragma unroll
  for (int mf = 0; mf < 8; ++mf) { acc[mf][0] = (f32x4)0.f; acc[mf][1] = (f32x4)0.f; }

  for (int s = 0; s < 16; ++s) {
    const float* c0 = B0 + (size_t)s * 32 * H;
    const float* c1 = B1 + (size_t)s * 32 * H;
    float g0 = c0[0],            g1 = c0[(size_t)1 * H], g2 = c0[(size_t)2 * H], g3 = c0[(size_t)3 * H];
    float g4 = c0[(size_t)4 * H], g5 = c0[(size_t)5 * H], g6 = c0[(size_t)6 * H], g7 = c0[(size_t)7 * H];
    float u0 = c1[0],            u1 = c1[(size_t)1 * H], u2 = c1[(size_t)2 * H], u3 = c1[(size_t)3 * H];
    float u4 = c1[(size_t)4 * H], u5 = c1[(size_t)5 * H], u6 = c1[(size_t)6 * H], u7 = c1[(size_t)7 * H];
    union { u32x4 u; bf16x8 h; } cg, cu;
    cg.u[0] = pkbf(g0, g1); cg.u[1] = pkbf(g2, g3);
    cg.u[2] = pkbf(g4, g5); cg.u[3] = pkbf(g6, g7);
    cu.u[0] = pkbf(u0, u1); cu.u[1] = pkbf(u2, u3);
    cu.u[2] = pkbf(u4, u5); cu.u[3] = pkbf(u6, u7);
    bf16x8 b0 = cg.h, b1 = cu.h;
    #pragma unroll
    for (int mf = 0; mf < 8; ++mf) {
      bf16x8 af = *(const bf16x8*)(ax[mf] + s * 32);
      acc[mf][0] = MFMA16(af, b0, acc[mf][0]);
      acc[mf][1] = MFMA16(af, b1, acc[mf][1]);
    }
  }

  #pragma unroll
  for (int mf = 0; mf < 8; ++mf) {
    #pragma unroll
    for (int cf = 0; cf < 2; ++cf) {
      int col = p * 32 + cf * 16 + lr;
      #pragma unroll
      for (int r = 0; r < 4; ++r) {
        int sl = m0 + mf * 16 + lg * 4 + r;
        if (sl < n) {
          int slot = sb + sl;
          atomicAdd(&out[(size_t)gtok[slot] * H + col], gws[slot] * acc[mf][cf][r]);
        }
      }
    }
  }
}

extern "C" void kernel_launch(void* const* d_in, const int* in_sizes, int n_in,
                              void* d_out, int out_size, void* d_ws, size_t ws_size,
                              hipStream_t stream)
{
  const float* x   = (const float*)d_in[0];
  const float* gw  = (const float*)d_in[1];
  const float* wgu = (const float*)d_in[2];
  const float* wdn = (const float*)d_in[3];
  float* out = (float*)d_out;
  float* logits = out + (size_t)T * H;

  char* w = (char*)d_ws;
  int*   cnt = (int*)(w);
  int*   bs  = (int*)(w + 32);
  int*   te  = (int*)(w + 64);
  int*   tr  = (int*)(w + 64 + 8192);
  float* tw  = (float*)(w + 64 + 16384);
  int*   gt  = (int*)(w + 64 + 24576);
  float* gwt = (float*)(w + 64 + 32768);
  unsigned short* act = (unsigned short*)(w + 65536);      // 2048x3584 bf16 = 14.68 MB
  unsigned short* xb  = (unsigned short*)(w + 14745600);   // 1024x1024 bf16 = 2 MB

  hipMemsetAsync(d_out, 0, (size_t)T * H * sizeof(float), stream);
  hipMemsetAsync(cnt, 0, NE * sizeof(int), stream);
  cvtx_k<<<512, 256, 0, stream>>>(x, xb);
  router_k<<<T, 64, 0, stream>>>(x, gw, logits, cnt, te, tr, tw);
  build_k<<<1, 1024, 0, stream>>>(cnt, bs, te, tr, tw, gt, gwt);
  ffn1_k<<<7168, 64, 0, stream>>>(xb, wgu, cnt, bs, gt, act);
  ffn2_k<<<7168, 64, 0, stream>>>(act, wdn, cnt, bs, gt, gwt, out);
}